// Round 5
// baseline (356.230 us; speedup 1.0000x reference)
//
#include <hip/hip_runtime.h>
#include <math.h>

#define N_NODES 50000
#define M_PAD   50048            /* 391*128 = 782*64 */
#define N_EDGES 800000
#define EP (N_EDGES + N_NODES)
#define DIN 256
#define HEADS 4
#define HID 64
#define F1 256
#define F2 128
#define NEG_SLOPE 0.2f
#define SCAN_NBLK ((N_NODES + 255)/256)   /* 196 */

typedef short bf16x8 __attribute__((ext_vector_type(8)));
typedef float f32x4  __attribute__((ext_vector_type(4)));

static __device__ __forceinline__ float leaky(float x){ return x > 0.f ? x : NEG_SLOPE*x; }
static __device__ __forceinline__ float elu_f(float x){ return x > 0.f ? x : (__expf(x)-1.f); }
static __device__ __forceinline__ float b2f(unsigned short u){ return __uint_as_float(((unsigned)u)<<16); }
static __device__ __forceinline__ unsigned short f2b(float f){
  unsigned u = __float_as_uint(f);
  return (unsigned short)((u + 0x7fffu + ((u>>16)&1u)) >> 16);   // RNE
}

// ---------------- CSR build ----------------
__global__ __launch_bounds__(256) void k_hist(const int* __restrict__ dst, int* __restrict__ counts){
  int e = blockIdx.x*256 + threadIdx.x;
  if (e >= EP) return;
  int d = (e < N_EDGES) ? dst[e] : (e - N_EDGES);
  atomicAdd(&counts[d], 1);
}

__global__ __launch_bounds__(256) void k_scan1(const int* __restrict__ counts,
                                               int* __restrict__ exc, int* __restrict__ bsum){
  int i = blockIdx.x*256 + threadIdx.x;
  int v = (i < N_NODES) ? counts[i] : 0;
  int lane = threadIdx.x & 63, wave = threadIdx.x >> 6;
  int inc = v;
  #pragma unroll
  for (int off=1; off<64; off<<=1){
    int n = __shfl_up(inc, off);
    if (lane >= off) inc += n;
  }
  __shared__ int wsum[4];
  if (lane == 63) wsum[wave] = inc;
  __syncthreads();
  int wpre = 0;
  #pragma unroll
  for (int w=0; w<4; w++) if (w < wave) wpre += wsum[w];
  if (i < N_NODES) exc[i] = wpre + inc - v;
  if (threadIdx.x == 255) bsum[blockIdx.x] = wpre + inc;
}

__global__ __launch_bounds__(256) void k_scan2(const int* __restrict__ bsum,
                                               int* __restrict__ bpref, int* __restrict__ offsets){
  int i = threadIdx.x;
  int v = (i < SCAN_NBLK) ? bsum[i] : 0;
  int lane = threadIdx.x & 63, wave = threadIdx.x >> 6;
  int inc = v;
  #pragma unroll
  for (int off=1; off<64; off<<=1){
    int n = __shfl_up(inc, off);
    if (lane >= off) inc += n;
  }
  __shared__ int wsum[4];
  if (lane == 63) wsum[wave] = inc;
  __syncthreads();
  int wpre = 0;
  #pragma unroll
  for (int w=0; w<4; w++) if (w < wave) wpre += wsum[w];
  if (i < SCAN_NBLK) bpref[i] = wpre + inc - v;
  if (i == 255) offsets[N_NODES] = wpre + inc;
}

__global__ __launch_bounds__(256) void k_scan3(const int* __restrict__ exc, const int* __restrict__ bpref,
                                               int* __restrict__ offsets, int* __restrict__ cursor){
  int i = blockIdx.x*256 + threadIdx.x;
  if (i >= N_NODES) return;
  int o = exc[i] + bpref[blockIdx.x];
  offsets[i] = o;
  cursor[i] = o;
}

__global__ __launch_bounds__(256) void k_scatter(const int* __restrict__ src, const int* __restrict__ dst,
                          int* __restrict__ cursor, int* __restrict__ sorted_src){
  int e = blockIdx.x*256 + threadIdx.x;
  if (e >= EP) return;
  int s, d;
  if (e < N_EDGES){ s = src[e]; d = dst[e]; } else { s = d = e - N_EDGES; }
  int pos = atomicAdd(&cursor[d], 1);
  sorted_src[pos] = s;
}

// ---------------- split f32 -> bf16 hi/lo ----------------
__global__ __launch_bounds__(256) void k_splitA(const float* __restrict__ X,
                         unsigned short* __restrict__ Ahi, unsigned short* __restrict__ Alo){
  int gid = blockIdx.x*256 + threadIdx.x;
  size_t base = (size_t)gid*4;
  int row = (int)(base >> 8);
  ushort4 hi, lo;
  if (row < N_NODES){
    float4 v = *(const float4*)(X + base);
    hi.x=f2b(v.x); hi.y=f2b(v.y); hi.z=f2b(v.z); hi.w=f2b(v.w);
    lo.x=f2b(v.x-b2f(hi.x)); lo.y=f2b(v.y-b2f(hi.y));
    lo.z=f2b(v.z-b2f(hi.z)); lo.w=f2b(v.w-b2f(hi.w));
  } else {
    hi = {0,0,0,0}; lo = {0,0,0,0};
  }
  *(ushort4*)(Ahi + base) = hi;
  *(ushort4*)(Alo + base) = lo;
}

__global__ __launch_bounds__(256) void k_splitWT(const float* __restrict__ W,
                          unsigned short* __restrict__ Bhi, unsigned short* __restrict__ Blo,
                          int Kd, int Nd){
  int t = blockIdx.x*256 + threadIdx.x;
  if (t >= Kd*Nd) return;
  int n = t / Kd, k = t % Kd;
  float v = W[(size_t)k*Nd + n];
  unsigned short hi = f2b(v);
  unsigned short lo = f2b(v - b2f(hi));
  Bhi[(size_t)n*Kd + k] = hi;
  Blo[(size_t)n*Kd + k] = lo;
}

// ---------------- bf16x3 MFMA GEMM; wave-grid WRxWC, each wave 64x64 ----------------
template<int WR, int WC>
__global__ __launch_bounds__(256) void k_gemm_bf3(
    const unsigned short* __restrict__ Ahi, const unsigned short* __restrict__ Alo,
    const unsigned short* __restrict__ Bthi, const unsigned short* __restrict__ Btlo,
    unsigned short* __restrict__ Cbf, int Nc){
  const int K = 256;
  int tid = threadIdx.x;
  int wave = tid>>6, lane = tid&63;
  int wr = wave / WC, wc = wave % WC;
  int row0 = blockIdx.x*(WR*64) + wr*64;
  int col0 = blockIdx.y*(WC*64) + wc*64;
  int lrow = lane&15, lk = (lane>>4)*8;
  f32x4 acc[4][4] = {};
  for (int ks=0; ks<K; ks+=32){
    bf16x8 ah[4], al[4], bh[4], bl[4];
    #pragma unroll
    for (int i=0;i<4;i++){
      size_t aoff = (size_t)(row0 + i*16 + lrow)*K + ks + lk;
      ah[i] = *(const bf16x8*)(Ahi + aoff);
      al[i] = *(const bf16x8*)(Alo + aoff);
      size_t boff = (size_t)(col0 + i*16 + lrow)*K + ks + lk;
      bh[i] = *(const bf16x8*)(Bthi + boff);
      bl[i] = *(const bf16x8*)(Btlo + boff);
    }
    #pragma unroll
    for (int i=0;i<4;i++)
      #pragma unroll
      for (int j=0;j<4;j++)
        acc[i][j] = __builtin_amdgcn_mfma_f32_16x16x32_bf16(ah[i], bh[j], acc[i][j], 0,0,0);
    #pragma unroll
    for (int i=0;i<4;i++)
      #pragma unroll
      for (int j=0;j<4;j++)
        acc[i][j] = __builtin_amdgcn_mfma_f32_16x16x32_bf16(ah[i], bl[j], acc[i][j], 0,0,0);
    #pragma unroll
    for (int i=0;i<4;i++)
      #pragma unroll
      for (int j=0;j<4;j++)
        acc[i][j] = __builtin_amdgcn_mfma_f32_16x16x32_bf16(al[i], bh[j], acc[i][j], 0,0,0);
  }
  int crow = (lane>>4)*4, ccol = lane&15;
  #pragma unroll
  for (int i=0;i<4;i++)
    #pragma unroll
    for (int j=0;j<4;j++)
      #pragma unroll
      for (int q=0;q<4;q++){
        int r = row0 + i*16 + crow + q;
        int c = col0 + j*16 + ccol;
        Cbf[(size_t)r*Nc + c] = f2b(acc[i][j][q]);
      }
}

// ---------------- attention dot products (bf16 features) ----------------
__global__ __launch_bounds__(256) void k_edot1(const unsigned short* __restrict__ h1bf, const float* __restrict__ a_src,
                        const float* __restrict__ a_dst, float* __restrict__ es, float* __restrict__ ed){
  int wave = threadIdx.x>>6, lane = threadIdx.x&63;
  int n = blockIdx.x*4 + wave;
  if (n >= N_NODES) return;
  ushort4 hv = ((const ushort4*)(h1bf + (size_t)n*F1))[lane];
  float4 s4 = ((const float4*)a_src)[lane];
  float4 d4 = ((const float4*)a_dst)[lane];
  float h0=b2f(hv.x), h1=b2f(hv.y), h2=b2f(hv.z), h3=b2f(hv.w);
  float ps = h0*s4.x + h1*s4.y + h2*s4.z + h3*s4.w;
  float pd = h0*d4.x + h1*d4.y + h2*d4.z + h3*d4.w;
  #pragma unroll
  for (int m=1;m<16;m<<=1){ ps += __shfl_xor(ps,m); pd += __shfl_xor(pd,m); }
  if ((lane&15)==0){ es[n*HEADS + (lane>>4)] = ps; ed[n*HEADS + (lane>>4)] = pd; }
}

__global__ __launch_bounds__(256) void k_edot2(const unsigned short* __restrict__ h2bf, const float* __restrict__ a_src,
                        const float* __restrict__ a_dst, float* __restrict__ es, float* __restrict__ ed){
  int wave=threadIdx.x>>6, lane=threadIdx.x&63;
  int n = blockIdx.x*4+wave; if (n>=N_NODES) return;
  ushort2 hv = ((const ushort2*)(h2bf + (size_t)n*F2))[lane];
  float2 s2 = ((const float2*)a_src)[lane];
  float2 d2 = ((const float2*)a_dst)[lane];
  float h0=b2f(hv.x), h1=b2f(hv.y);
  float ps = h0*s2.x + h1*s2.y;
  float pd = h0*d2.x + h1*d2.y;
  #pragma unroll
  for (int m=1;m<64;m<<=1){ ps += __shfl_xor(ps,m); pd += __shfl_xor(pd,m); }
  if (lane==0){ es[n]=ps; ed[n]=pd; }
}

// ---------------- layer-1 aggregation: no-shift softmax, unroll-8 gather ----------------
__global__ __launch_bounds__(256) void k_agg1(const unsigned short* __restrict__ h1bf, const float* __restrict__ es,
                       const float* __restrict__ ed, const int* __restrict__ offsets,
                       const int* __restrict__ ssrc, const float* __restrict__ b1,
                       unsigned short* __restrict__ A2hi, unsigned short* __restrict__ A2lo){
  __shared__ float alds[4][64][4];
  int wave = threadIdx.x>>6, lane = threadIdx.x&63;
  int d = blockIdx.x*4 + wave;
  if (d >= M_PAD) return;
  if (d >= N_NODES){
    ushort4 z = {0,0,0,0};
    ((ushort4*)(A2hi + (size_t)d*F1))[lane] = z;
    ((ushort4*)(A2lo + (size_t)d*F1))[lane] = z;
    return;
  }
  int beg = offsets[d], end = offsets[d+1];
  int deg = end - beg;
  float4 edv = *(const float4*)(ed + d*4);
  // pass 1: plain sum of exp(leaky(logit)) — logits bounded (~|3|), shift-free softmax is exact
  float s0=0.f,s1=0.f,s2=0.f,s3=0.f;
  float4 myex = {0,0,0,0};
  for (int j=lane; j<deg; j+=64){
    int sn = ssrc[beg+j];
    float4 ev = *(const float4*)(es + (size_t)sn*4);
    float4 ex;
    ex.x = __expf(leaky(ev.x+edv.x)); ex.y = __expf(leaky(ev.y+edv.y));
    ex.z = __expf(leaky(ev.z+edv.z)); ex.w = __expf(leaky(ev.w+edv.w));
    if (j == lane) myex = ex;
    s0+=ex.x; s1+=ex.y; s2+=ex.z; s3+=ex.w;
  }
  #pragma unroll
  for (int off=1; off<64; off<<=1){
    s0 += __shfl_xor(s0,off); s1 += __shfl_xor(s1,off);
    s2 += __shfl_xor(s2,off); s3 += __shfl_xor(s3,off);
  }
  float i0=1.f/(s0+1e-16f), i1=1.f/(s1+1e-16f), i2=1.f/(s2+1e-16f), i3=1.f/(s3+1e-16f);
  int n1 = deg < 64 ? deg : 64;
  if (lane < n1){
    alds[wave][lane][0] = myex.x*i0;
    alds[wave][lane][1] = myex.y*i1;
    alds[wave][lane][2] = myex.z*i2;
    alds[wave][lane][3] = myex.w*i3;
  }
  asm volatile("s_waitcnt lgkmcnt(0)" ::: "memory");
  int head = lane>>4;
  float4 acc0={0,0,0,0}, acc1={0,0,0,0}, acc2={0,0,0,0}, acc3={0,0,0,0};
  int j=0;
  for (; j+8<=n1; j+=8){
    int sn[8]; float a[8]; ushort4 v[8];
    #pragma unroll
    for (int u=0;u<8;u++) sn[u] = ssrc[beg+j+u];
    #pragma unroll
    for (int u=0;u<8;u++){
      a[u] = alds[wave][j+u][head];
      v[u] = ((const ushort4*)(h1bf + (size_t)sn[u]*F1))[lane];
    }
    #pragma unroll
    for (int u=0;u<8;u++){
      float4* ac = (u&3)==0?&acc0:((u&3)==1?&acc1:((u&3)==2?&acc2:&acc3));
      ac->x=fmaf(a[u],b2f(v[u].x),ac->x); ac->y=fmaf(a[u],b2f(v[u].y),ac->y);
      ac->z=fmaf(a[u],b2f(v[u].z),ac->z); ac->w=fmaf(a[u],b2f(v[u].w),ac->w);
    }
  }
  for (; j<n1; j++){
    int sn=ssrc[beg+j];
    float a=alds[wave][j][head];
    ushort4 v = ((const ushort4*)(h1bf + (size_t)sn*F1))[lane];
    acc0.x=fmaf(a,b2f(v.x),acc0.x); acc0.y=fmaf(a,b2f(v.y),acc0.y);
    acc0.z=fmaf(a,b2f(v.z),acc0.z); acc0.w=fmaf(a,b2f(v.w),acc0.w);
  }
  if (deg > 64){
    float ih = head==0?i0:(head==1?i1:(head==2?i2:i3));
    float eh = head==0?edv.x:(head==1?edv.y:(head==2?edv.z:edv.w));
    for (j=64; j<deg; j++){
      int sn=ssrc[beg+j];
      float e = es[(size_t)sn*4+head];
      float a = __expf(leaky(e+eh))*ih;
      ushort4 v = ((const ushort4*)(h1bf + (size_t)sn*F1))[lane];
      acc0.x=fmaf(a,b2f(v.x),acc0.x); acc0.y=fmaf(a,b2f(v.y),acc0.y);
      acc0.z=fmaf(a,b2f(v.z),acc0.z); acc0.w=fmaf(a,b2f(v.w),acc0.w);
    }
  }
  float4 acc;
  acc.x = acc0.x+acc1.x+acc2.x+acc3.x;
  acc.y = acc0.y+acc1.y+acc2.y+acc3.y;
  acc.z = acc0.z+acc1.z+acc2.z+acc3.z;
  acc.w = acc0.w+acc1.w+acc2.w+acc3.w;
  float4 bb = *(const float4*)(b1 + lane*4);
  float4 o;
  o.x = elu_f(acc.x + bb.x);
  o.y = elu_f(acc.y + bb.y);
  o.z = elu_f(acc.z + bb.z);
  o.w = elu_f(acc.w + bb.w);
  ushort4 hi, lo;
  hi.x=f2b(o.x); lo.x=f2b(o.x-b2f(hi.x));
  hi.y=f2b(o.y); lo.y=f2b(o.y-b2f(hi.y));
  hi.z=f2b(o.z); lo.z=f2b(o.z-b2f(hi.z));
  hi.w=f2b(o.w); lo.w=f2b(o.w-b2f(hi.w));
  ((ushort4*)(A2hi + (size_t)d*F1))[lane] = hi;
  ((ushort4*)(A2lo + (size_t)d*F1))[lane] = lo;
}

// ---------------- layer-2 aggregation + final mean ----------------
__global__ __launch_bounds__(256) void k_agg2(const unsigned short* __restrict__ h2bf, const float* __restrict__ es,
                       const float* __restrict__ ed, const int* __restrict__ offsets,
                       const int* __restrict__ ssrc, const float* __restrict__ b2,
                       float* __restrict__ out){
  __shared__ float alds[4][64];
  int wave=threadIdx.x>>6, lane=threadIdx.x&63;
  int d = blockIdx.x*4+wave; if (d>=N_NODES) return;
  int beg=offsets[d], end=offsets[d+1];
  int deg=end-beg;
  float edv = ed[d];
  float s=0.f, myex=0.f;
  for (int j=lane;j<deg;j+=64){
    float e = __expf(leaky(es[ssrc[beg+j]] + edv));
    if (j==lane) myex = e;
    s += e;
  }
  #pragma unroll
  for (int off=1;off<64;off<<=1) s += __shfl_xor(s,off);
  float inv = 1.f/(s+1e-16f);
  int n1 = deg < 64 ? deg : 64;
  if (lane < n1) alds[wave][lane] = myex*inv;
  asm volatile("s_waitcnt lgkmcnt(0)" ::: "memory");
  float2 acc0={0,0}, acc1={0,0}, acc2={0,0}, acc3={0,0};
  int j=0;
  for (; j+8<=n1; j+=8){
    int sn[8]; float a[8]; ushort2 v[8];
    #pragma unroll
    for (int u=0;u<8;u++) sn[u]=ssrc[beg+j+u];
    #pragma unroll
    for (int u=0;u<8;u++){
      a[u]=alds[wave][j+u];
      v[u]=((const ushort2*)(h2bf + (size_t)sn[u]*F2))[lane];
    }
    #pragma unroll
    for (int u=0;u<8;u++){
      float2* ac = (u&3)==0?&acc0:((u&3)==1?&acc1:((u&3)==2?&acc2:&acc3));
      ac->x=fmaf(a[u],b2f(v[u].x),ac->x); ac->y=fmaf(a[u],b2f(v[u].y),ac->y);
    }
  }
  for (; j<n1; j++){
    int sn=ssrc[beg+j];
    float a=alds[wave][j];
    ushort2 v = ((const ushort2*)(h2bf + (size_t)sn*F2))[lane];
    acc0.x=fmaf(a,b2f(v.x),acc0.x); acc0.y=fmaf(a,b2f(v.y),acc0.y);
  }
  if (deg > 64){
    for (j=64; j<deg; j++){
      int sn=ssrc[beg+j];
      float a = __expf(leaky(es[sn]+edv))*inv;
      ushort2 v = ((const ushort2*)(h2bf + (size_t)sn*F2))[lane];
      acc0.x=fmaf(a,b2f(v.x),acc0.x); acc0.y=fmaf(a,b2f(v.y),acc0.y);
    }
  }
  float2 acc;
  acc.x = acc0.x+acc1.x+acc2.x+acc3.x;
  acc.y = acc0.y+acc1.y+acc2.y+acc3.y;
  float2 bb = *(const float2*)(b2 + lane*2);
  float r = elu_f(acc.x+bb.x) + elu_f(acc.y+bb.y);
  #pragma unroll
  for (int off=1;off<64;off<<=1) r += __shfl_xor(r,off);
  if (lane==0) out[d] = r * (1.f/128.f);
}

extern "C" void kernel_launch(void* const* d_in, const int* in_sizes, int n_in,
                              void* d_out, int out_size, void* d_ws, size_t ws_size,
                              hipStream_t stream) {
  const float* x   = (const float*)d_in[0];
  const int*   ei  = (const int*)d_in[1];
  const int*   esrc = ei;
  const int*   edst = ei + N_EDGES;
  const float* W1  = (const float*)d_in[2];
  const float* a1s = (const float*)d_in[3];
  const float* a1d = (const float*)d_in[4];
  const float* b1  = (const float*)d_in[5];
  const float* W2  = (const float*)d_in[6];
  const float* a2s = (const float*)d_in[7];
  const float* a2d = (const float*)d_in[8];
  const float* b2  = (const float*)d_in[9];
  float* out = (float*)d_out;

  char* ws = (char*)d_ws;
  size_t off = 0;
  auto alloc = [&](size_t bytes)->void*{ void* p = ws + off; off += (bytes + 255) & ~(size_t)255; return p; };
  unsigned short* A1hi = (unsigned short*)alloc((size_t)M_PAD*F1*2);
  unsigned short* A1lo = (unsigned short*)alloc((size_t)M_PAD*F1*2);
  unsigned short* h1bf = (unsigned short*)alloc((size_t)M_PAD*F1*2);
  unsigned short* h2bf = (unsigned short*)alloc((size_t)M_PAD*F2*2);
  unsigned short* Bt1hi= (unsigned short*)alloc((size_t)F1*DIN*2);
  unsigned short* Bt1lo= (unsigned short*)alloc((size_t)F1*DIN*2);
  unsigned short* Bt2hi= (unsigned short*)alloc((size_t)F2*F1*2);
  unsigned short* Bt2lo= (unsigned short*)alloc((size_t)F2*F1*2);
  float* e1s   = (float*)alloc((size_t)N_NODES*HEADS*4);
  float* e1d   = (float*)alloc((size_t)N_NODES*HEADS*4);
  float* e2s   = (float*)alloc((size_t)N_NODES*4);
  float* e2d   = (float*)alloc((size_t)N_NODES*4);
  int*   counts= (int*)alloc((size_t)N_NODES*4);
  int*   offs  = (int*)alloc((size_t)(N_NODES+1)*4);
  int*   cursor= (int*)alloc((size_t)N_NODES*4);
  int*   exc   = (int*)alloc((size_t)N_NODES*4);
  int*   bsum  = (int*)alloc((size_t)SCAN_NBLK*4);
  int*   bpref = (int*)alloc((size_t)SCAN_NBLK*4);
  int*   ssrc  = (int*)alloc((size_t)EP*4);
  unsigned short* A2hi = A1hi;
  unsigned short* A2lo = A1lo;

  hipMemsetAsync(counts, 0, (size_t)N_NODES*4, stream);
  k_hist<<<(EP+255)/256, 256, 0, stream>>>(edst, counts);
  k_scan1<<<SCAN_NBLK, 256, 0, stream>>>(counts, exc, bsum);
  k_scan2<<<1, 256, 0, stream>>>(bsum, bpref, offs);
  k_scan3<<<SCAN_NBLK, 256, 0, stream>>>(exc, bpref, offs, cursor);
  k_scatter<<<(EP+255)/256, 256, 0, stream>>>(esrc, edst, cursor, ssrc);

  k_splitA<<<(M_PAD*F1/4 + 255)/256, 256, 0, stream>>>(x, A1hi, A1lo);
  k_splitWT<<<(DIN*F1 + 255)/256, 256, 0, stream>>>(W1, Bt1hi, Bt1lo, DIN, F1);
  k_splitWT<<<(F1*F2 + 255)/256, 256, 0, stream>>>(W2, Bt2hi, Bt2lo, F1, F2);

  dim3 g1(M_PAD/64, 1);
  k_gemm_bf3<1,4><<<g1, 256, 0, stream>>>(A1hi, A1lo, Bt1hi, Bt1lo, h1bf, F1);
  k_edot1<<<(N_NODES+3)/4, 256, 0, stream>>>(h1bf, a1s, a1d, e1s, e1d);
  k_agg1<<<(M_PAD+3)/4, 256, 0, stream>>>(h1bf, e1s, e1d, offs, ssrc, b1, A2hi, A2lo);

  dim3 g2(M_PAD/128, 1);
  k_gemm_bf3<2,2><<<g2, 256, 0, stream>>>(A2hi, A2lo, Bt2hi, Bt2lo, h2bf, F2);
  k_edot2<<<(N_NODES+3)/4, 256, 0, stream>>>(h2bf, a2s, a2d, e2s, e2d);
  k_agg2<<<(N_NODES+3)/4, 256, 0, stream>>>(h2bf, e2s, e2d, offs, ssrc, b2, out);
}